// Round 11
// baseline (308.771 us; speedup 1.0000x reference)
//
#include <hip/hip_runtime.h>
#include <hip/hip_bf16.h>
#include <math.h>

constexpr int F   = 1433;
constexpr int NB  = 64;
constexpr int KN  = 8;
constexpr int BF  = NB * F;            // 91712
constexpr float EPS = 1e-5f;

constexpr int SF  = 16;                // splits for k_D / k_y1
constexpr int CH  = 90;                // 16*90 = 1440 >= F
constexpr int SK  = 15;                // gemm g-splits: 15*96 = 1440 (pad-guarded)
constexpr int NST = 256;               // stats blocks

// Workspace (float offsets); ws is 256 MiB
constexpr int O_YS  = 0;                       // [BF]
constexpr int O_DP  = O_YS + BF;               // [SF*BF] D partials
constexpr int O_Y1P = O_DP + SF * BF;          // [SF*BF] y1 partials
constexpr int O_P   = O_Y1P + SF * BF;         // [4*BF]  float4 (x,ys,w,q)
constexpr int O_Y1  = O_P + 4 * BF;            // [BF]
constexpr int O_Y2  = O_Y1 + BF;               // [2*BF]
constexpr int O_G2P = O_Y2 + 2 * BF;           // [SK*128*F] gemm partials
constexpr int O_ST  = O_G2P + SK * 128 * F;    // [64] stats

// ---------------- K0: ys[b,g] = sum_k neighbor[b,k,g]; zero stats ----------
__global__ __launch_bounds__(256) void k_ys(const float* __restrict__ nbr,
                                            float* __restrict__ ys,
                                            float* __restrict__ st) {
  if (blockIdx.x == 0 && threadIdx.x < 64) st[threadIdx.x] = 0.f;
  int i = blockIdx.x * 256 + threadIdx.x;
  if (i >= BF) return;
  int b = i / F, g = i - b * F;
  const float* p = nbr + (size_t)b * KN * F + g;
  float s = 0.f;
#pragma unroll
  for (int k = 0; k < KN; ++k) s += p[k * F];
  ys[i] = s;
}

// ---------------- K1: D partials, chunk-only staging ----------------
__global__ __launch_bounds__(256) void k_D(const float* __restrict__ x,
                                           const float* __restrict__ ys,
                                           float* __restrict__ DP) {
  __shared__ __align__(8) float2 xyc[CH];
  const int b = blockIdx.x, s = blockIdx.y;
  const int cs = s * CH, cn = min(CH, F - cs);
  for (int i = threadIdx.x; i < cn; i += 256)
    xyc[i] = make_float2(x[b * F + cs + i], ys[b * F + cs + i]);
  __syncthreads();
  float gx[6], gy[6], acc[6] = {};
#pragma unroll
  for (int j = 0; j < 6; ++j) {
    int g = threadIdx.x + 256 * j;
    gx[j] = (g < F) ? x[b * F + g] : 0.f;
    gy[j] = (g < F) ? ys[b * F + g] : 0.f;
  }
#pragma unroll 6
  for (int i = 0; i < cn; ++i) {
    float2 p = xyc[i];   // broadcast, conflict-free
#pragma unroll
    for (int j = 0; j < 6; ++j)
      acc[j] += __builtin_amdgcn_sqrtf(fmaf(gy[j], p.x, gx[j] * p.y));
  }
#pragma unroll
  for (int j = 0; j < 6; ++j) {
    int g = threadIdx.x + 256 * j;
    if (g < F) DP[(size_t)s * BF + b * F + g] = acc[j];
  }
}

// ---------------- K2: y1 partials; D-reduce -> P for own chunk -------------
__global__ __launch_bounds__(256) void k_y1(const float* __restrict__ x,
                                            const float* __restrict__ ys,
                                            const float* __restrict__ DP,
                                            float* __restrict__ Y1P,
                                            float4* __restrict__ P) {
  __shared__ __align__(16) float4 pl[CH];
  const int b = blockIdx.x, s = blockIdx.y;
  const int cs = s * CH, cn = min(CH, F - cs);
  for (int i = threadIdx.x; i < cn; i += 256) {
    int g = cs + i;
    float d = 0.f;
#pragma unroll
    for (int t = 0; t < SF; ++t) d += DP[(size_t)t * BF + b * F + g];
    float inv = (d > 0.f) ? 1.f / d : 0.f;
    float xv = x[b * F + g], yv = ys[b * F + g];
    float4 pv = make_float4(xv, yv, xv * inv, inv);
    pl[i] = pv;
    P[b * F + g] = pv;
  }
  __syncthreads();
  float fx[6], fy[6], acc[6] = {};
#pragma unroll
  for (int j = 0; j < 6; ++j) {
    int f = threadIdx.x + 256 * j;
    fx[j] = (f < F) ? x[b * F + f] : 0.f;
    fy[j] = (f < F) ? ys[b * F + f] : 0.f;
  }
#pragma unroll 6
  for (int i = 0; i < cn; ++i) {
    float4 p = pl[i];   // broadcast
#pragma unroll
    for (int j = 0; j < 6; ++j)
      acc[j] = fmaf(__builtin_amdgcn_sqrtf(fmaf(fx[j], p.y, fy[j] * p.x)), p.z, acc[j]);
  }
#pragma unroll
  for (int j = 0; j < 6; ++j) {
    int f = threadIdx.x + 256 * j;
    if (f < F) Y1P[(size_t)s * BF + b * F + f] = acc[j];
  }
}

// ---------------- K3: stats1 — y1 = x + sum Y1P; sum/sumsq -----------------
__global__ __launch_bounds__(256) void k_s1(const float* __restrict__ x,
                                            const float* __restrict__ Y1P,
                                            float* __restrict__ y1,
                                            float* __restrict__ st) {
  float sv = 0.f, sq = 0.f;
  for (int i = blockIdx.x * 256 + threadIdx.x; i < BF; i += NST * 256) {
    float v = x[i];
#pragma unroll
    for (int t = 0; t < SF; ++t) v += Y1P[(size_t)t * BF + i];
    y1[i] = v;
    sv += v; sq += v * v;
  }
#pragma unroll
  for (int o = 32; o; o >>= 1) {
    sv += __shfl_down(sv, o, 64);
    sq += __shfl_down(sq, o, 64);
  }
  __shared__ float ls[4], lq[4];
  int wave = threadIdx.x >> 6, lane = threadIdx.x & 63;
  if (lane == 0) { ls[wave] = sv; lq[wave] = sq; }
  __syncthreads();
  if (threadIdx.x == 0) {
    atomicAdd(&st[0], ls[0] + ls[1] + ls[2] + ls[3]);
    atomicAdd(&st[1], lq[0] + lq[1] + lq[2] + lq[3]);
  }
}

// ---------------- K4: fused A-on-the-fly gemm -------------------------------
// Block (ft, sk): computes A[f0..f0+31][gs..gs+95] in fp32 from P, H from y1,
// accumulates G2P[sk][m][f] = sum_g A[f,g]*H[m,g].
__global__ __launch_bounds__(256, 4) void k_gemmA(const float4* __restrict__ P,
                                                  const float* __restrict__ y1,
                                                  const float* __restrict__ st,
                                                  const float* __restrict__ W1,
                                                  const float* __restrict__ g1,
                                                  const float* __restrict__ be1,
                                                  float* __restrict__ G2P) {
  const float mu = st[0] / (float)BF;
  const float var = st[1] / (float)BF - mu * mu;
  const float wa = W1[0], wb = W1[1];
  const float k0 = wa * g1[0] / sqrtf(wa * wa * var + EPS);
  const float k1 = wb * g1[1] / sqrtf(wb * wb * var + EPS);
  const float c0 = -k0 * mu + be1[0];
  const float c1 = -k1 * mu + be1[1];

  __shared__ __align__(16) float4 Pb[32 * 32];   // [b-half][g] 16 KB
  __shared__ __align__(16) float Al[32 * 36];    // [g][f] 4.6 KB
  __shared__ __align__(16) float Hl[32 * 132];   // [g][m] 16.9 KB
  const int f0 = blockIdx.x * 32;
  const int gs = blockIdx.y * 96;
  const int tid = threadIdx.x;
  const int git = tid >> 3;              // A-phase: g within chunk (0..31)
  const int fq  = tid & 7;               // A-phase: f group
  const int fsub = fq * 4;               // 4 f's (also MAC f's)
  const int msub = (tid >> 3) * 4;       // MAC: 4 m's
  const int hb = tid & 7, hg = tid >> 3; // H staging

  // per-thread f-side constants (clamped; pad f guarded at store)
  float xf[4], yf[4];
#pragma unroll
  for (int j = 0; j < 4; ++j) {
    int f = min(f0 + fsub + j, F - 1);
    xf[j] = P[f].x;                      // b=0 row: P[0*F+f] = (x[0,f], ys[0,f],..)
    yf[j] = P[f].y;
  }
  // NOTE: xf/yf must be x[b? f]... A's f-side uses x[b][f],ys[b][f] per b!
  // (handled below: f-side values vary with b, so load from P[b*F+f] via LDS-free
  //  register reads is wrong; instead we use the symmetric form with Pb only.)

  float acc[4][4] = {};
  for (int c = 0; c < 3; ++c) {
    const int gb = gs + c * 32;
    float a[4] = {0.f, 0.f, 0.f, 0.f};
    for (int half = 0; half < 2; ++half) {
      const int b0 = half * 32;
      __syncthreads();                   // Pb free (prev readers done)
#pragma unroll
      for (int r = 0; r < 4; ++r) {      // stage Pb: 32 b x 32 g
        int idx = tid + 256 * r;
        int bb = idx >> 5, gg = idx & 31;
        int g = gb + gg;
        float4 pv = P[(size_t)(b0 + bb) * F + min(g, F - 1)];
        if (g >= F) pv.w = 0.f;          // pad g: q=0 kills the column
        Pb[bb * 32 + gg] = pv;
      }
      __syncthreads();
      // A-accumulate over this b-half; f-side (x,ys) read per b from P (L2-hot)
      for (int bb = 0; bb < 32; ++bb) {
        const int b = b0 + bb;
        // f-side values for this b: 4 clamped reads (coalesced-ish, L2 hit)
        float4 pf0 = P[(size_t)b * F + min(f0 + fsub + 0, F - 1)];
        float4 pf1 = P[(size_t)b * F + min(f0 + fsub + 1, F - 1)];
        float4 pf2 = P[(size_t)b * F + min(f0 + fsub + 2, F - 1)];
        float4 pf3 = P[(size_t)b * F + min(f0 + fsub + 3, F - 1)];
        float4 pg = Pb[bb * 32 + git];   // broadcast among 8 lanes
        float t0 = fmaf(pf0.x, pg.y, pf0.y * pg.x);
        float t1 = fmaf(pf1.x, pg.y, pf1.y * pg.x);
        float t2 = fmaf(pf2.x, pg.y, pf2.y * pg.x);
        float t3 = fmaf(pf3.x, pg.y, pf3.y * pg.x);
        a[0] = fmaf(__builtin_amdgcn_sqrtf(t0), pg.w, a[0]);
        a[1] = fmaf(__builtin_amdgcn_sqrtf(t1), pg.w, a[1]);
        a[2] = fmaf(__builtin_amdgcn_sqrtf(t2), pg.w, a[2]);
        a[3] = fmaf(__builtin_amdgcn_sqrtf(t3), pg.w, a[3]);
      }
    }
    // write A-subtile and H, then MAC
    *(float4*)&Al[git * 36 + fsub] = make_float4(a[0], a[1], a[2], a[3]);
    {
      const int gl = min(gb + hg, F - 1);
#pragma unroll
      for (int r = 0; r < 8; ++r) {
        const int bb = hb + 8 * r;
        const float v = y1[bb * F + gl];
        float h0 = fmaf(k0, v, c0); h0 = h0 / (1.f + fabsf(h0));
        float h1 = fmaf(k1, v, c1); h1 = h1 / (1.f + fabsf(h1));
        *(float2*)&Hl[hg * 132 + 2 * bb] = make_float2(h0, h1);
      }
    }
    __syncthreads();
#pragma unroll 4
    for (int gi = 0; gi < 32; ++gi) {
      float4 a4 = *(const float4*)&Al[gi * 36 + fsub];
      float4 h4 = *(const float4*)&Hl[gi * 132 + msub];
      float av[4] = {a4.x, a4.y, a4.z, a4.w};
      float hv[4] = {h4.x, h4.y, h4.z, h4.w};
#pragma unroll
      for (int i = 0; i < 4; ++i)
#pragma unroll
        for (int j = 0; j < 4; ++j)
          acc[i][j] = fmaf(av[i], hv[j], acc[i][j]);
    }
  }
  float* dst = G2P + (size_t)blockIdx.y * 128 * F;
#pragma unroll
  for (int i = 0; i < 4; ++i) {
    int f = f0 + fsub + i;
    if (f < F) {
#pragma unroll
      for (int j = 0; j < 4; ++j)
        dst[(msub + j) * F + f] = acc[i][j];
    }
  }
}

// ---------------- K5: reduce partials + 64*H diag -> y2, moments ----------
__global__ __launch_bounds__(256) void k_stats2(const float* __restrict__ y1,
                                                const float* __restrict__ G2P,
                                                const float* __restrict__ st,
                                                const float* __restrict__ W1,
                                                const float* __restrict__ g1,
                                                const float* __restrict__ be1,
                                                float* __restrict__ y2,
                                                float* __restrict__ stw) {
  const float mu = st[0] / (float)BF;
  const float var = st[1] / (float)BF - mu * mu;
  const float wa = W1[0], wb = W1[1];
  const float k0 = wa * g1[0] / sqrtf(wa * wa * var + EPS);
  const float k1 = wb * g1[1] / sqrtf(wb * wb * var + EPS);
  const float c0 = -k0 * mu + be1[0];
  const float c1 = -k1 * mu + be1[1];

  float su = 0.f, sv = 0.f, suu = 0.f, svv = 0.f, suv = 0.f;
  for (int i = blockIdx.x * 256 + threadIdx.x; i < BF; i += gridDim.x * 256) {
    int b = i / F, f = i - b * F;
    float w = y1[i];
    float h0 = fmaf(k0, w, c0); h0 = h0 / (1.f + fabsf(h0));
    float h1 = fmaf(k1, w, c1); h1 = h1 / (1.f + fabsf(h1));
    int iu = (2 * b) * F + f, iv = iu + F;
    float u = 64.f * h0, v = 64.f * h1;
#pragma unroll
    for (int t = 0; t < SK; ++t) {
      u += G2P[(size_t)t * 128 * F + iu];
      v += G2P[(size_t)t * 128 * F + iv];
    }
    y2[iu] = u; y2[iv] = v;
    su += u; sv += v; suu += u * u; svv += v * v; suv += u * v;
  }
#pragma unroll
  for (int o = 32; o; o >>= 1) {
    su += __shfl_down(su, o, 64);
    sv += __shfl_down(sv, o, 64);
    suu += __shfl_down(suu, o, 64);
    svv += __shfl_down(svv, o, 64);
    suv += __shfl_down(suv, o, 64);
  }
  __shared__ float red[5][4];
  int wave = threadIdx.x >> 6, lane = threadIdx.x & 63;
  if (lane == 0) {
    red[0][wave] = su; red[1][wave] = sv; red[2][wave] = suu;
    red[3][wave] = svv; red[4][wave] = suv;
  }
  __syncthreads();
  if (threadIdx.x == 0) {
#pragma unroll
    for (int m = 0; m < 5; ++m)
      atomicAdd(&stw[2 + m], red[m][0] + red[m][1] + red[m][2] + red[m][3]);
  }
}

// ---------------- K6: final classifier (BN2 consts inline) ----------------
__global__ __launch_bounds__(256) void k_out(const float* __restrict__ y2,
                                             const float* __restrict__ st,
                                             const float* __restrict__ W2,
                                             const float* __restrict__ b2,
                                             const float* __restrict__ g2,
                                             const float* __restrict__ be2,
                                             const float* __restrict__ Wc,
                                             const float* __restrict__ bc,
                                             float* __restrict__ out) {
  float n = (float)BF;
  float Eu = st[2] / n, Ev = st[3] / n;
  float Euu = st[4] / n, Evv = st[5] / n, Euv = st[6] / n;
  float cA[2], cB[2], cC[2];
#pragma unroll
  for (int o = 0; o < 2; ++o) {
    float w0 = W2[o * 2 + 0], w1 = W2[o * 2 + 1];
    float mean = w0 * Eu + w1 * Ev + b2[o];
    float Eh2 = w0 * w0 * Euu + 2.f * w0 * w1 * Euv + w1 * w1 * Evv +
                2.f * b2[o] * (w0 * Eu + w1 * Ev) + b2[o] * b2[o];
    float vr = Eh2 - mean * mean;
    float inv = g2[o] / sqrtf(vr + EPS);
    cA[o] = w0 * inv;
    cB[o] = w1 * inv;
    cC[o] = (b2[o] - mean) * inv + be2[o];
  }
  const int b = blockIdx.x;
  float acc[7] = {};
  for (int f = threadIdx.x; f < F; f += 256) {
    float u = y2[(2 * b) * F + f], v = y2[(2 * b + 1) * F + f];
    float h0 = fmaf(cA[0], u, fmaf(cB[0], v, cC[0]));
    h0 = h0 / (1.f + fabsf(h0));
    float h1 = fmaf(cA[1], u, fmaf(cB[1], v, cC[1]));
    h1 = h1 / (1.f + fabsf(h1));
#pragma unroll
    for (int o = 0; o < 7; ++o) acc[o] = fmaf(Wc[o * (2 * F) + f], h0, acc[o]);
#pragma unroll
    for (int o = 0; o < 7; ++o) acc[o] = fmaf(Wc[o * (2 * F) + F + f], h1, acc[o]);
  }
#pragma unroll
  for (int o = 0; o < 7; ++o) {
#pragma unroll
    for (int s = 32; s; s >>= 1) acc[o] += __shfl_down(acc[o], s, 64);
  }
  __shared__ float red[7][4];
  int wave = threadIdx.x >> 6, lane = threadIdx.x & 63;
  if (lane == 0) {
#pragma unroll
    for (int o = 0; o < 7; ++o) red[o][wave] = acc[o];
  }
  __syncthreads();
  if (threadIdx.x < 7) {
    int o = threadIdx.x;
    out[b * 7 + o] = red[o][0] + red[o][1] + red[o][2] + red[o][3] + bc[o];
  }
}

extern "C" void kernel_launch(void* const* d_in, const int* in_sizes, int n_in,
                              void* d_out, int out_size, void* d_ws, size_t ws_size,
                              hipStream_t stream) {
  const float* x    = (const float*)d_in[0];
  const float* nbr  = (const float*)d_in[1];
  const float* W1   = (const float*)d_in[3];
  const float* W2   = (const float*)d_in[5];
  const float* b2   = (const float*)d_in[6];
  const float* g1   = (const float*)d_in[7];
  const float* be1  = (const float*)d_in[8];
  const float* g2   = (const float*)d_in[9];
  const float* be2  = (const float*)d_in[10];
  const float* Wc   = (const float*)d_in[11];
  const float* bc   = (const float*)d_in[12];
  float* out = (float*)d_out;
  float* ws  = (float*)d_ws;

  float*  ys  = ws + O_YS;
  float*  DP  = ws + O_DP;
  float*  Y1P = ws + O_Y1P;
  float4* P   = (float4*)(ws + O_P);
  float*  y1  = ws + O_Y1;
  float*  y2  = ws + O_Y2;
  float*  G2P = ws + O_G2P;
  float*  st  = ws + O_ST;

  k_ys    <<<(BF + 255) / 256, 256, 0, stream>>>(nbr, ys, st);
  k_D     <<<dim3(NB, SF), 256, 0, stream>>>(x, ys, DP);
  k_y1    <<<dim3(NB, SF), 256, 0, stream>>>(x, ys, DP, Y1P, P);
  k_s1    <<<NST, 256, 0, stream>>>(x, Y1P, y1, st);
  k_gemmA <<<dim3(45, SK), 256, 0, stream>>>(P, y1, st, W1, g1, be1, G2P);
  k_stats2<<<NST, 256, 0, stream>>>(y1, G2P, st, W1, g1, be1, y2, st);
  k_out   <<<NB, 256, 0, stream>>>(y2, st, W2, b2, g2, be2, Wc, bc, out);
}

// Round 12
// 203.727 us; speedup vs baseline: 1.5156x; 1.5156x over previous
//
#include <hip/hip_runtime.h>
#include <hip/hip_bf16.h>
#include <math.h>

constexpr int F   = 1433;
constexpr int NB  = 64;
constexpr int KN  = 8;
constexpr int BF  = NB * F;            // 91712
constexpr float EPS = 1e-5f;

constexpr int SF  = 16;                // splits for k_D / k_y1
constexpr int CH  = 90;                // 16*90 = 1440 >= F
constexpr int AbS = 1440;              // Ab row stride (zero-padded)
constexpr int SK  = 15;                // gemm splits: 15*96 = 1440
constexpr int FT  = 12;                // A f-tile: 120 tiles * 6 gx = 720
constexpr int NA  = 720;
constexpr int NST = 256;               // stats blocks

// Workspace (float offsets); ws is 256 MiB
constexpr int O_YS  = 0;                       // [BF]
constexpr int O_DP  = O_YS + BF;               // [SF*BF] D partials
constexpr int O_Y1P = O_DP + SF * BF;          // [SF*BF] y1 partials
constexpr int O_P   = O_Y1P + SF * BF;         // [4*BF]  float4 (x,ys,w,q)
constexpr int O_Y1  = O_P + 4 * BF;            // [BF]
constexpr int O_Y2  = O_Y1 + BF;               // [2*BF]
constexpr int O_G2P = O_Y2 + 2 * BF;           // [SK*128*F] gemm partials
constexpr int O_AB  = O_G2P + SK * 128 * F;    // [F*AbS halfs] bf16 A
constexpr int O_ST  = O_AB + (F * AbS) / 2;    // [64] stats

// ---------------- K1: D partials; ys recomputed in-block (s==0 persists) ---
// DP[s][b,g] = sum_{f in chunk s} sqrt(ys_g*x_f + x_g*ys_f)
__global__ __launch_bounds__(256) void k_D(const float* __restrict__ x,
                                           const float* __restrict__ nbr,
                                           float* __restrict__ DP,
                                           float* __restrict__ ys_out,
                                           float* __restrict__ st) {
  const int b = blockIdx.x, s = blockIdx.y;
  if (b == 0 && s == 0 && threadIdx.x < 64) st[threadIdx.x] = 0.f;
  __shared__ __align__(8) float2 xyc[CH];
  const int cs = s * CH, cn = min(CH, F - cs);
  for (int i = threadIdx.x; i < cn; i += 256) {
    const float* p = nbr + (size_t)b * KN * F + cs + i;
    float a = 0.f;
#pragma unroll
    for (int k = 0; k < KN; ++k) a += p[k * F];
    xyc[i] = make_float2(x[b * F + cs + i], a);
  }
  __syncthreads();
  float gx[6], gy[6], acc[6] = {};
#pragma unroll
  for (int j = 0; j < 6; ++j) {
    int g = threadIdx.x + 256 * j;
    int gc = min(g, F - 1);
    const float* p = nbr + (size_t)b * KN * F + gc;
    float a = 0.f;
#pragma unroll
    for (int k = 0; k < KN; ++k) a += p[k * F];
    gx[j] = (g < F) ? x[b * F + gc] : 0.f;
    gy[j] = (g < F) ? a : 0.f;
  }
  if (s == 0) {
#pragma unroll
    for (int j = 0; j < 6; ++j) {
      int g = threadIdx.x + 256 * j;
      if (g < F) ys_out[b * F + g] = gy[j];
    }
  }
#pragma unroll 6
  for (int i = 0; i < cn; ++i) {
    float2 p = xyc[i];   // broadcast, conflict-free
#pragma unroll
    for (int j = 0; j < 6; ++j)
      acc[j] += __builtin_amdgcn_sqrtf(fmaf(gy[j], p.x, gx[j] * p.y));
  }
#pragma unroll
  for (int j = 0; j < 6; ++j) {
    int g = threadIdx.x + 256 * j;
    if (g < F) DP[(size_t)s * BF + b * F + g] = acc[j];
  }
}

// ---------------- K2: y1 partials; D-reduce -> P for own chunk -------------
__global__ __launch_bounds__(256) void k_y1(const float* __restrict__ x,
                                            const float* __restrict__ ys,
                                            const float* __restrict__ DP,
                                            float* __restrict__ Y1P,
                                            float4* __restrict__ P) {
  __shared__ __align__(16) float4 pl[CH];
  const int b = blockIdx.x, s = blockIdx.y;
  const int cs = s * CH, cn = min(CH, F - cs);
  for (int i = threadIdx.x; i < cn; i += 256) {
    int g = cs + i;
    float d = 0.f;
#pragma unroll
    for (int t = 0; t < SF; ++t) d += DP[(size_t)t * BF + b * F + g];
    float inv = (d > 0.f) ? 1.f / d : 0.f;
    float xv = x[b * F + g], yv = ys[b * F + g];
    float4 pv = make_float4(xv, yv, xv * inv, inv);
    pl[i] = pv;
    P[b * F + g] = pv;
  }
  __syncthreads();
  float fx[6], fy[6], acc[6] = {};
#pragma unroll
  for (int j = 0; j < 6; ++j) {
    int f = threadIdx.x + 256 * j;
    fx[j] = (f < F) ? x[b * F + f] : 0.f;
    fy[j] = (f < F) ? ys[b * F + f] : 0.f;
  }
#pragma unroll 6
  for (int i = 0; i < cn; ++i) {
    float4 p = pl[i];   // broadcast
#pragma unroll
    for (int j = 0; j < 6; ++j)
      acc[j] = fmaf(__builtin_amdgcn_sqrtf(fmaf(fx[j], p.y, fy[j] * p.x)), p.z, acc[j]);
  }
#pragma unroll
  for (int j = 0; j < 6; ++j) {
    int f = threadIdx.x + 256 * j;
    if (f < F) Y1P[(size_t)s * BF + b * F + f] = acc[j];
  }
}

// ---------------- K3: fused A-build (720 blocks) + stats1 (256 blocks) -----
__global__ __launch_bounds__(256) void k_Astats(const float* __restrict__ x,
                                                const float* __restrict__ ys,
                                                const float4* __restrict__ P,
                                                const float* __restrict__ Y1P,
                                                __hip_bfloat16* __restrict__ Ab,
                                                float* __restrict__ y1,
                                                float* __restrict__ st) {
  const int bid = blockIdx.x;
  if (bid < NA) {
    __shared__ float2 fxy[FT][NB];   // 6 KB
    const int gxc = bid % 6, fy = bid / 6;
    const int fbase = fy * FT;
#pragma unroll
    for (int r = 0; r < 3; ++r) {    // FT*NB = 768
      int i = threadIdx.x + 256 * r;
      int j = i >> 6, bb = i & 63;
      int f = fbase + j;
      float vx = 0.f, vy = 0.f;
      if (f < F) { vx = x[bb * F + f]; vy = ys[bb * F + f]; }
      fxy[j][bb] = make_float2(vx, vy);
    }
    __syncthreads();
    const int g = gxc * 256 + threadIdx.x;
    if (g >= AbS) return;
    if (g < F) {
      float acc[FT] = {};
      float4 cur[4], nxt[4];
#pragma unroll
      for (int t = 0; t < 4; ++t) cur[t] = P[t * F + g];       // b = 0..3
      for (int bb = 0; bb < NB; bb += 4) {
        if (bb + 4 < NB) {
#pragma unroll
          for (int t = 0; t < 4; ++t) nxt[t] = P[(bb + 4 + t) * F + g];
        }
#pragma unroll
        for (int t = 0; t < 4; ++t) {
          float4 pc = cur[t];
#pragma unroll
          for (int j = 0; j < FT; ++j) {
            float2 w = fxy[j][bb + t];   // broadcast
            acc[j] = fmaf(__builtin_amdgcn_sqrtf(fmaf(w.x, pc.y, pc.x * w.y)), pc.w, acc[j]);
          }
        }
#pragma unroll
        for (int t = 0; t < 4; ++t) cur[t] = nxt[t];
      }
#pragma unroll
      for (int j = 0; j < FT; ++j) {
        int f = fbase + j;
        if (f < F) Ab[(size_t)f * AbS + g] = __float2bfloat16(acc[j]);
      }
    } else {                         // zero pad cols [F, AbS)
#pragma unroll
      for (int j = 0; j < FT; ++j) {
        int f = fbase + j;
        if (f < F) Ab[(size_t)f * AbS + g] = __float2bfloat16(0.f);
      }
    }
  } else {
    const int sid = bid - NA;
    float sv = 0.f, sq = 0.f;
    for (int i = sid * 256 + threadIdx.x; i < BF; i += NST * 256) {
      float v = x[i];
#pragma unroll
      for (int t = 0; t < SF; ++t) v += Y1P[(size_t)t * BF + i];
      y1[i] = v;
      sv += v; sq += v * v;
    }
#pragma unroll
    for (int o = 32; o; o >>= 1) {
      sv += __shfl_down(sv, o, 64);
      sq += __shfl_down(sq, o, 64);
    }
    __shared__ float ls[4], lq[4];
    int wave = threadIdx.x >> 6, lane = threadIdx.x & 63;
    if (lane == 0) { ls[wave] = sv; lq[wave] = sq; }
    __syncthreads();
    if (threadIdx.x == 0) {
      atomicAdd(&st[0], ls[0] + ls[1] + ls[2] + ls[3]);
      atomicAdd(&st[1], lq[0] + lq[1] + lq[2] + lq[3]);
    }
  }
}

// ---------------- K4: gemm, single-buffer + reg prefetch, 4 blocks/CU ------
__global__ __launch_bounds__(256, 4) void k_gemm(const ushort* __restrict__ Ab,
                                                 const float* __restrict__ y1,
                                                 const float* __restrict__ st,
                                                 const float* __restrict__ W1,
                                                 const float* __restrict__ g1,
                                                 const float* __restrict__ be1,
                                                 float* __restrict__ G2P) {
  const float mu = st[0] / (float)BF;
  const float var = st[1] / (float)BF - mu * mu;
  const float wa = W1[0], wb = W1[1];
  const float k0 = wa * g1[0] / sqrtf(wa * wa * var + EPS);
  const float k1 = wb * g1[1] / sqrtf(wb * wb * var + EPS);
  const float c0 = -k0 * mu + be1[0];
  const float c1 = -k1 * mu + be1[1];

  __shared__ __align__(16) float Al[32 * 36];    // 4.6 KB
  __shared__ __align__(16) float Hl[32 * 132];   // 16.9 KB
  const int f0 = blockIdx.x * 32;
  const int gs = blockIdx.y * 96;
  const int tid = threadIdx.x;
  const int ffs = tid >> 3, g4s = (tid & 7) * 4;
  const int hb = tid & 7, hg = tid >> 3;
  const int fsub = (tid & 7) * 4, msub = (tid >> 3) * 4;

  uint2 pa; float pyv[8];
  auto loadRegs = [&](int gb) {
    const int f = f0 + ffs;
    pa = make_uint2(0u, 0u);
    if (f < F) pa = *(const uint2*)&Ab[(size_t)f * AbS + gb + g4s];
    const int gl = min(gb + hg, F - 1);   // pad cols of A are 0
#pragma unroll
    for (int r = 0; r < 8; ++r) pyv[r] = y1[(hb + 8 * r) * F + gl];
  };
  auto storeLDS = [&]() {
    Al[(g4s + 0) * 36 + ffs] = __uint_as_float(pa.x << 16);
    Al[(g4s + 1) * 36 + ffs] = __uint_as_float(pa.x & 0xffff0000u);
    Al[(g4s + 2) * 36 + ffs] = __uint_as_float(pa.y << 16);
    Al[(g4s + 3) * 36 + ffs] = __uint_as_float(pa.y & 0xffff0000u);
#pragma unroll
    for (int r = 0; r < 8; ++r) {
      const int bb = hb + 8 * r;
      const float v = pyv[r];
      float h0 = fmaf(k0, v, c0); h0 = h0 / (1.f + fabsf(h0));
      float h1 = fmaf(k1, v, c1); h1 = h1 / (1.f + fabsf(h1));
      *(float2*)&Hl[hg * 132 + 2 * bb] = make_float2(h0, h1);
    }
  };

  float acc[4][4] = {};
  loadRegs(gs);
  for (int c = 0; c < 3; ++c) {
    if (c) __syncthreads();           // previous compute done -> LDS reusable
    storeLDS();
    __syncthreads();
    if (c < 2) loadRegs(gs + (c + 1) * 32);   // next chunk in flight
#pragma unroll 4
    for (int gi = 0; gi < 32; ++gi) {
      float4 a4 = *(const float4*)&Al[gi * 36 + fsub];
      float4 h4 = *(const float4*)&Hl[gi * 132 + msub];
      float av[4] = {a4.x, a4.y, a4.z, a4.w};
      float hv[4] = {h4.x, h4.y, h4.z, h4.w};
#pragma unroll
      for (int i = 0; i < 4; ++i)
#pragma unroll
        for (int j = 0; j < 4; ++j)
          acc[i][j] = fmaf(av[i], hv[j], acc[i][j]);
    }
  }
  float* dst = G2P + (size_t)blockIdx.y * 128 * F;
#pragma unroll
  for (int i = 0; i < 4; ++i) {
    int f = f0 + fsub + i;
    if (f < F) {
#pragma unroll
      for (int j = 0; j < 4; ++j)
        dst[(msub + j) * F + f] = acc[i][j];
    }
  }
}

// ---------------- K5: reduce partials + 64*H diag -> y2, moments ----------
__global__ __launch_bounds__(256) void k_stats2(const float* __restrict__ y1,
                                                const float* __restrict__ G2P,
                                                const float* __restrict__ st,
                                                const float* __restrict__ W1,
                                                const float* __restrict__ g1,
                                                const float* __restrict__ be1,
                                                float* __restrict__ y2,
                                                float* __restrict__ stw) {
  const float mu = st[0] / (float)BF;
  const float var = st[1] / (float)BF - mu * mu;
  const float wa = W1[0], wb = W1[1];
  const float k0 = wa * g1[0] / sqrtf(wa * wa * var + EPS);
  const float k1 = wb * g1[1] / sqrtf(wb * wb * var + EPS);
  const float c0 = -k0 * mu + be1[0];
  const float c1 = -k1 * mu + be1[1];

  float su = 0.f, sv = 0.f, suu = 0.f, svv = 0.f, suv = 0.f;
  for (int i = blockIdx.x * 256 + threadIdx.x; i < BF; i += gridDim.x * 256) {
    int b = i / F, f = i - b * F;
    float w = y1[i];
    float h0 = fmaf(k0, w, c0); h0 = h0 / (1.f + fabsf(h0));
    float h1 = fmaf(k1, w, c1); h1 = h1 / (1.f + fabsf(h1));
    int iu = (2 * b) * F + f, iv = iu + F;
    float u = 64.f * h0, v = 64.f * h1;
#pragma unroll
    for (int t = 0; t < SK; ++t) {
      u += G2P[(size_t)t * 128 * F + iu];
      v += G2P[(size_t)t * 128 * F + iv];
    }
    y2[iu] = u; y2[iv] = v;
    su += u; sv += v; suu += u * u; svv += v * v; suv += u * v;
  }
#pragma unroll
  for (int o = 32; o; o >>= 1) {
    su += __shfl_down(su, o, 64);
    sv += __shfl_down(sv, o, 64);
    suu += __shfl_down(suu, o, 64);
    svv += __shfl_down(svv, o, 64);
    suv += __shfl_down(suv, o, 64);
  }
  __shared__ float red[5][4];
  int wave = threadIdx.x >> 6, lane = threadIdx.x & 63;
  if (lane == 0) {
    red[0][wave] = su; red[1][wave] = sv; red[2][wave] = suu;
    red[3][wave] = svv; red[4][wave] = suv;
  }
  __syncthreads();
  if (threadIdx.x == 0) {
#pragma unroll
    for (int m = 0; m < 5; ++m)
      atomicAdd(&stw[2 + m], red[m][0] + red[m][1] + red[m][2] + red[m][3]);
  }
}

// ---------------- K6: final classifier (BN2 consts inline) ----------------
__global__ __launch_bounds__(256) void k_out(const float* __restrict__ y2,
                                             const float* __restrict__ st,
                                             const float* __restrict__ W2,
                                             const float* __restrict__ b2,
                                             const float* __restrict__ g2,
                                             const float* __restrict__ be2,
                                             const float* __restrict__ Wc,
                                             const float* __restrict__ bc,
                                             float* __restrict__ out) {
  float n = (float)BF;
  float Eu = st[2] / n, Ev = st[3] / n;
  float Euu = st[4] / n, Evv = st[5] / n, Euv = st[6] / n;
  float cA[2], cB[2], cC[2];
#pragma unroll
  for (int o = 0; o < 2; ++o) {
    float w0 = W2[o * 2 + 0], w1 = W2[o * 2 + 1];
    float mean = w0 * Eu + w1 * Ev + b2[o];
    float Eh2 = w0 * w0 * Euu + 2.f * w0 * w1 * Euv + w1 * w1 * Evv +
                2.f * b2[o] * (w0 * Eu + w1 * Ev) + b2[o] * b2[o];
    float vr = Eh2 - mean * mean;
    float inv = g2[o] / sqrtf(vr + EPS);
    cA[o] = w0 * inv;
    cB[o] = w1 * inv;
    cC[o] = (b2[o] - mean) * inv + be2[o];
  }
  const int b = blockIdx.x;
  float acc[7] = {};
  for (int f = threadIdx.x; f < F; f += 256) {
    float u = y2[(2 * b) * F + f], v = y2[(2 * b + 1) * F + f];
    float h0 = fmaf(cA[0], u, fmaf(cB[0], v, cC[0]));
    h0 = h0 / (1.f + fabsf(h0));
    float h1 = fmaf(cA[1], u, fmaf(cB[1], v, cC[1]));
    h1 = h1 / (1.f + fabsf(h1));
#pragma unroll
    for (int o = 0; o < 7; ++o) acc[o] = fmaf(Wc[o * (2 * F) + f], h0, acc[o]);
#pragma unroll
    for (int o = 0; o < 7; ++o) acc[o] = fmaf(Wc[o * (2 * F) + F + f], h1, acc[o]);
  }
#pragma unroll
  for (int o = 0; o < 7; ++o) {
#pragma unroll
    for (int s = 32; s; s >>= 1) acc[o] += __shfl_down(acc[o], s, 64);
  }
  __shared__ float red[7][4];
  int wave = threadIdx.x >> 6, lane = threadIdx.x & 63;
  if (lane == 0) {
#pragma unroll
    for (int o = 0; o < 7; ++o) red[o][wave] = acc[o];
  }
  __syncthreads();
  if (threadIdx.x < 7) {
    int o = threadIdx.x;
    out[b * 7 + o] = red[o][0] + red[o][1] + red[o][2] + red[o][3] + bc[o];
  }
}

extern "C" void kernel_launch(void* const* d_in, const int* in_sizes, int n_in,
                              void* d_out, int out_size, void* d_ws, size_t ws_size,
                              hipStream_t stream) {
  const float* x    = (const float*)d_in[0];
  const float* nbr  = (const float*)d_in[1];
  const float* W1   = (const float*)d_in[3];
  const float* W2   = (const float*)d_in[5];
  const float* b2   = (const float*)d_in[6];
  const float* g1   = (const float*)d_in[7];
  const float* be1  = (const float*)d_in[8];
  const float* g2   = (const float*)d_in[9];
  const float* be2  = (const float*)d_in[10];
  const float* Wc   = (const float*)d_in[11];
  const float* bc   = (const float*)d_in[12];
  float* out = (float*)d_out;
  float* ws  = (float*)d_ws;

  float*  ys  = ws + O_YS;
  float*  DP  = ws + O_DP;
  float*  Y1P = ws + O_Y1P;
  float4* P   = (float4*)(ws + O_P);
  float*  y1  = ws + O_Y1;
  float*  y2  = ws + O_Y2;
  float*  G2P = ws + O_G2P;
  __hip_bfloat16* Ab = (__hip_bfloat16*)(ws + O_AB);
  float*  st  = ws + O_ST;

  k_D     <<<dim3(NB, SF), 256, 0, stream>>>(x, nbr, DP, ys, st);
  k_y1    <<<dim3(NB, SF), 256, 0, stream>>>(x, ys, DP, Y1P, P);
  k_Astats<<<NA + NST, 256, 0, stream>>>(x, ys, P, Y1P, Ab, y1, st);
  k_gemm  <<<dim3(45, SK), 256, 0, stream>>>((const ushort*)Ab, y1, st, W1, g1, be1, G2P);
  k_stats2<<<NST, 256, 0, stream>>>(y1, G2P, st, W1, g1, be1, y2, st);
  k_out   <<<NB, 256, 0, stream>>>(y2, st, W2, b2, g2, be2, Wc, bc, out);
}